// Round 1
// baseline (649.993 us; speedup 1.0000x reference)
//
#include <hip/hip_runtime.h>
#include <math.h>

// Kuramoto Euler integration, N=4096, 50 steps.
// coupling_i = cos(th_i) * (K @ sin(th))_i - sin(th_i) * (K @ cos(th))_i
// One wave (64 lanes) per row; 4 waves (4 rows) per 256-thread block.

#define NOSC 4096
#define NSTEPS 50
#define DTCONST 0.01f

__global__ __launch_bounds__(256) void kuramoto_init(
    const float* __restrict__ phases, float* __restrict__ theta,
    float* __restrict__ s, float* __restrict__ c) {
  int i = blockIdx.x * blockDim.x + threadIdx.x;
  if (i < NOSC) {
    float t = phases[i];
    theta[i] = t;
    s[i] = sinf(t);
    c[i] = cosf(t);
  }
}

__global__ __launch_bounds__(256) void kuramoto_step(
    const float* __restrict__ Kmat, const float* __restrict__ omegas,
    float* __restrict__ theta,
    const float* __restrict__ s_in, const float* __restrict__ c_in,
    float* __restrict__ s_out, float* __restrict__ c_out) {
  const int lane = threadIdx.x & 63;
  const int wave = threadIdx.x >> 6;
  const int row = (blockIdx.x << 2) + wave;

  const float4* __restrict__ K4 =
      reinterpret_cast<const float4*>(Kmat + (size_t)row * NOSC);
  const float4* __restrict__ s4 = reinterpret_cast<const float4*>(s_in);
  const float4* __restrict__ c4 = reinterpret_cast<const float4*>(c_in);

  float accS = 0.f, accC = 0.f;
  // 4096 elems / row = 1024 float4; 64 lanes -> 16 float4 per lane.
  #pragma unroll
  for (int ch = 0; ch < 16; ++ch) {
    const int idx = (ch << 6) + lane;   // coalesced: 64 lanes x 16B = 1KB/instr
    float4 k  = K4[idx];
    float4 sv = s4[idx];
    float4 cv = c4[idx];
    accS = fmaf(k.x, sv.x, accS); accS = fmaf(k.y, sv.y, accS);
    accS = fmaf(k.z, sv.z, accS); accS = fmaf(k.w, sv.w, accS);
    accC = fmaf(k.x, cv.x, accC); accC = fmaf(k.y, cv.y, accC);
    accC = fmaf(k.z, cv.z, accC); accC = fmaf(k.w, cv.w, accC);
  }
  // wave-64 reduction
  #pragma unroll
  for (int off = 32; off > 0; off >>= 1) {
    accS += __shfl_down(accS, off);
    accC += __shfl_down(accC, off);
  }
  if (lane == 0) {
    float t  = theta[row];
    float si = s_in[row], ci = c_in[row];
    float coupling = ci * accS - si * accC;
    float tn = t + DTCONST * (omegas[row] + coupling);
    theta[row] = tn;                    // only this wave touches row -> safe
    s_out[row] = sinf(tn);
    c_out[row] = cosf(tn);
  }
}

__global__ __launch_bounds__(256) void kuramoto_out(
    const float* __restrict__ theta, float* __restrict__ out) {
  int i = blockIdx.x * blockDim.x + threadIdx.x;
  if (i < NOSC) out[i] = theta[i];
}

extern "C" void kernel_launch(void* const* d_in, const int* in_sizes, int n_in,
                              void* d_out, int out_size, void* d_ws, size_t ws_size,
                              hipStream_t stream) {
  const float* phases = (const float*)d_in[0];
  const float* Kmat   = (const float*)d_in[1];
  const float* omegas = (const float*)d_in[2];
  float* out = (float*)d_out;

  float* ws    = (float*)d_ws;
  float* theta = ws;              // NOSC
  float* sb[2] = {ws + 1 * NOSC, ws + 3 * NOSC};
  float* cb[2] = {ws + 2 * NOSC, ws + 4 * NOSC};

  kuramoto_init<<<NOSC / 256, 256, 0, stream>>>(phases, theta, sb[0], cb[0]);
  for (int t = 0; t < NSTEPS; ++t) {
    kuramoto_step<<<NOSC / 4, 256, 0, stream>>>(
        Kmat, omegas, theta, sb[t & 1], cb[t & 1], sb[(t + 1) & 1], cb[(t + 1) & 1]);
  }
  kuramoto_out<<<NOSC / 256, 256, 0, stream>>>(theta, out);
}

// Round 3
// 302.253 us; speedup vs baseline: 2.1505x; 2.1505x over previous
//
#include <hip/hip_runtime.h>
#include <math.h>

// Kuramoto Euler integration, N=4096, 50 steps.
// coupling_i = cos(th_i)*(K@sin th)_i - sin(th_i)*(K@cos th)_i
// K converted to bf16 once per call (32 MiB -> halves per-step traffic and
// fits L2/L3). 512 blocks x 256 thr per step; 8 rows/block, 2 rows/wave
// sharing one LDS-staged s/c read (stride-1 ds_read_b128, conflict-free).

#define NOSC 4096
#define NSTEPS 50
#define DTF 0.01f

__global__ __launch_bounds__(256) void k_init(
    const float* __restrict__ phases, float* __restrict__ theta,
    float* __restrict__ s, float* __restrict__ c) {
  int i = blockIdx.x * blockDim.x + threadIdx.x;
  if (i < NOSC) {
    float t = phases[i];
    theta[i] = t;
    s[i] = sinf(t);
    c[i] = cosf(t);
  }
}

// fp32 -> bf16 (round-to-nearest-even), 4 elems per thread-iter
__global__ __launch_bounds__(256) void k_convert(
    const float4* __restrict__ K4, ushort4* __restrict__ Kb) {
  const int n4 = NOSC * NOSC / 4;
  for (int i = blockIdx.x * blockDim.x + threadIdx.x; i < n4;
       i += gridDim.x * blockDim.x) {
    float4 f = K4[i];
    ushort4 o;
    unsigned int b;
    b = __float_as_uint(f.x); b += 0x7FFFu + ((b >> 16) & 1u); o.x = (unsigned short)(b >> 16);
    b = __float_as_uint(f.y); b += 0x7FFFu + ((b >> 16) & 1u); o.y = (unsigned short)(b >> 16);
    b = __float_as_uint(f.z); b += 0x7FFFu + ((b >> 16) & 1u); o.z = (unsigned short)(b >> 16);
    b = __float_as_uint(f.w); b += 0x7FFFu + ((b >> 16) & 1u); o.w = (unsigned short)(b >> 16);
    Kb[i] = o;
  }
}

template <bool BF16K>
__global__ __launch_bounds__(256, 2) void k_step(
    const void* __restrict__ Kp, const float* __restrict__ omegas,
    float* __restrict__ theta,
    const float* __restrict__ s_in, const float* __restrict__ c_in,
    float* __restrict__ s_out, float* __restrict__ c_out) {
  __shared__ float s_lds[NOSC];
  __shared__ float c_lds[NOSC];
  const int lane = threadIdx.x & 63;
  const int wave = threadIdx.x >> 6;

  // stage s/c (16 KiB each) into LDS: 4 float4 per thread, coalesced
  float4* sl4 = reinterpret_cast<float4*>(s_lds);
  float4* cl4 = reinterpret_cast<float4*>(c_lds);
  const float4* sg4 = reinterpret_cast<const float4*>(s_in);
  const float4* cg4 = reinterpret_cast<const float4*>(c_in);
  #pragma unroll
  for (int i = 0; i < 4; ++i) {
    const int idx = i * 256 + threadIdx.x;
    sl4[idx] = sg4[idx];
    cl4[idx] = cg4[idx];
  }
  __syncthreads();

  const int row0 = (blockIdx.x << 3) + (wave << 1);  // 8 rows/block, 2/wave
  const int row1 = row0 + 1;

  float aS0 = 0.f, aC0 = 0.f, aS1 = 0.f, aC1 = 0.f;
  #pragma unroll
  for (int ch = 0; ch < 16; ++ch) {
    const int j4 = (ch << 6) + lane;   // float4 index; 16B/lane stride-1
    const float4 sv = sl4[j4];
    const float4 cv = cl4[j4];
    float k0x, k0y, k0z, k0w, k1x, k1y, k1z, k1w;
    if (BF16K) {
      const ushort4* __restrict__ Kb = reinterpret_cast<const ushort4*>(Kp);
      const ushort4 a = Kb[(size_t)row0 * (NOSC / 4) + j4];
      const ushort4 b = Kb[(size_t)row1 * (NOSC / 4) + j4];
      k0x = __uint_as_float((unsigned int)a.x << 16);
      k0y = __uint_as_float((unsigned int)a.y << 16);
      k0z = __uint_as_float((unsigned int)a.z << 16);
      k0w = __uint_as_float((unsigned int)a.w << 16);
      k1x = __uint_as_float((unsigned int)b.x << 16);
      k1y = __uint_as_float((unsigned int)b.y << 16);
      k1z = __uint_as_float((unsigned int)b.z << 16);
      k1w = __uint_as_float((unsigned int)b.w << 16);
    } else {
      const float4* __restrict__ Kf = reinterpret_cast<const float4*>(Kp);
      const float4 a = Kf[(size_t)row0 * (NOSC / 4) + j4];
      const float4 b = Kf[(size_t)row1 * (NOSC / 4) + j4];
      k0x = a.x; k0y = a.y; k0z = a.z; k0w = a.w;
      k1x = b.x; k1y = b.y; k1z = b.z; k1w = b.w;
    }
    aS0 = fmaf(k0x, sv.x, aS0); aS0 = fmaf(k0y, sv.y, aS0);
    aS0 = fmaf(k0z, sv.z, aS0); aS0 = fmaf(k0w, sv.w, aS0);
    aC0 = fmaf(k0x, cv.x, aC0); aC0 = fmaf(k0y, cv.y, aC0);
    aC0 = fmaf(k0z, cv.z, aC0); aC0 = fmaf(k0w, cv.w, aC0);
    aS1 = fmaf(k1x, sv.x, aS1); aS1 = fmaf(k1y, sv.y, aS1);
    aS1 = fmaf(k1z, sv.z, aS1); aS1 = fmaf(k1w, sv.w, aS1);
    aC1 = fmaf(k1x, cv.x, aC1); aC1 = fmaf(k1y, cv.y, aC1);
    aC1 = fmaf(k1z, cv.z, aC1); aC1 = fmaf(k1w, cv.w, aC1);
  }

  // wave-64 butterfly: all lanes end with full sums
  #pragma unroll
  for (int off = 32; off > 0; off >>= 1) {
    aS0 += __shfl_xor(aS0, off);
    aC0 += __shfl_xor(aC0, off);
    aS1 += __shfl_xor(aS1, off);
    aC1 += __shfl_xor(aC1, off);
  }

  const int myRow = (lane == 0) ? row0 : ((lane == 1) ? row1 : -1);
  if (myRow >= 0) {
    const float accS = (lane == 0) ? aS0 : aS1;
    const float accC = (lane == 0) ? aC0 : aC1;
    const float si = s_lds[myRow];
    const float ci = c_lds[myRow];
    const float tn =
        theta[myRow] + DTF * (omegas[myRow] + ci * accS - si * accC);
    theta[myRow] = tn;
    s_out[myRow] = sinf(tn);
    c_out[myRow] = cosf(tn);
  }
}

extern "C" void kernel_launch(void* const* d_in, const int* in_sizes, int n_in,
                              void* d_out, int out_size, void* d_ws, size_t ws_size,
                              hipStream_t stream) {
  const float* phases = (const float*)d_in[0];
  const float* Kmat   = (const float*)d_in[1];
  const float* omegas = (const float*)d_in[2];
  float* out = (float*)d_out;

  float* ws = (float*)d_ws;
  float* theta = ws;
  float* sb[2] = {ws + 1 * NOSC, ws + 3 * NOSC};
  float* cb[2] = {ws + 2 * NOSC, ws + 4 * NOSC};

  const size_t vecBytes = (size_t)5 * NOSC * sizeof(float);
  const size_t kbOff = (vecBytes + 255) & ~(size_t)255;
  const size_t kbBytes = (size_t)NOSC * NOSC * 2;
  const bool useBf16 = (ws_size >= kbOff + kbBytes);
  ushort4* Kb = (ushort4*)((char*)d_ws + kbOff);

  k_init<<<NOSC / 256, 256, 0, stream>>>(phases, theta, sb[0], cb[0]);
  if (useBf16) {
    k_convert<<<2048, 256, 0, stream>>>((const float4*)Kmat, Kb);
  }
  for (int t = 0; t < NSTEPS; ++t) {
    if (useBf16) {
      k_step<true><<<NOSC / 8, 256, 0, stream>>>(
          (const void*)Kb, omegas, theta, sb[t & 1], cb[t & 1],
          sb[(t + 1) & 1], cb[(t + 1) & 1]);
    } else {
      k_step<false><<<NOSC / 8, 256, 0, stream>>>(
          (const void*)Kmat, omegas, theta, sb[t & 1], cb[t & 1],
          sb[(t + 1) & 1], cb[(t + 1) & 1]);
    }
  }
  hipMemcpyAsync(out, theta, NOSC * sizeof(float), hipMemcpyDeviceToDevice,
                 stream);
}